// Round 1
// 1344.155 us; speedup vs baseline: 1.0104x; 1.0104x over previous
//
#include <hip/hip_runtime.h>
#include <cstdint>
#include <cstddef>

#define BATCH 8
#define CDIM 128
#define SEQ 2304
#define NEXP 3
#define HHID 8192
#define NPAR 16384
#define TK 64

typedef unsigned short u16;
typedef __attribute__((ext_vector_type(8))) __bf16 bf16x8;
typedef __attribute__((ext_vector_type(4))) float f32x4;

__device__ __forceinline__ unsigned short f2b(float f) {
    union { float f; unsigned int i; } v; v.f = f;
    unsigned int x = v.i;
    unsigned int r = (x + 0x7fffu + ((x >> 16) & 1u)) >> 16;
    return (unsigned short)r;
}
__device__ __forceinline__ float b2f(unsigned short u) {
    union { unsigned int i; float f; } v; v.i = ((unsigned int)u) << 16; return v.f;
}

// load a 128x128 bf16 weight matrix (pre-transposed [oc][i]) into 8 uint4 regs/thread
__device__ __forceinline__ void loadw(const u16* __restrict__ wsrc, int t, uint4* r) {
    #pragma unroll
    for (int j = 0; j < 8; ++j) {
        int idx = j * 256 + t;
        int oc = idx >> 4, i8 = (idx & 15) * 8;
        r[j] = *(const uint4*)(wsrc + oc * CDIM + i8);
    }
}
__device__ __forceinline__ void storew(u16 (*lw)[136], int t, const uint4* r) {
    #pragma unroll
    for (int j = 0; j < 8; ++j) {
        int idx = j * 256 + t;
        int oc = idx >> 4, i8 = (idx & 15) * 8;
        *(uint4*)(&lw[oc][i8]) = r[j];
    }
}

// ---------------- one-time weight prep: fp32 [i][oc] -> bf16 [oc][i] --------
// blocks 0..5: attn qw/kw/vw for 2 layers  (dst wTa[l*3+m])
// blocks 6..11: moe  ew1/ew2 for 3 experts (dst wTm[e*2+m])
__global__ __launch_bounds__(256) void k_wprep(const float* __restrict__ qw,
        const float* __restrict__ kw, const float* __restrict__ vw,
        const float* __restrict__ ew1, const float* __restrict__ ew2,
        u16* __restrict__ wTa, u16* __restrict__ wTm) {
    __shared__ float lt[64][132];
    int bid = blockIdx.x, t = threadIdx.x;
    const float* src; u16* dst;
    if (bid < 6) {
        int l = bid / 3, m = bid % 3;
        src = ((m == 0) ? qw : (m == 1) ? kw : vw) + l * CDIM * CDIM;
        dst = wTa + (size_t)bid * CDIM * CDIM;
    } else {
        int q = bid - 6; int e = q >> 1, m = q & 1;
        src = (m ? ew2 : ew1) + (size_t)e * CDIM * CDIM;
        dst = wTm + (size_t)q * CDIM * CDIM;
    }
    for (int h = 0; h < 2; ++h) {
        if (h) __syncthreads();
        for (int p = 0; p < 8; ++p) {
            int idx = p * 256 + t;
            int r = idx >> 5, c4 = (idx & 31) * 4;   // r: 0..63 (row h*64+r of src)
            *(float4*)(&lt[r][c4]) = *(const float4*)(src + (h * 64 + r) * CDIM + c4);
        }
        __syncthreads();
        for (int p = 0; p < 8; ++p) {
            int idx = p * 256 + t;
            int oc = idx >> 4, i4 = (idx & 15) * 4;  // i4: 0..60 within this half
            uint2 o;
            o.x = (unsigned int)f2b(lt[i4 + 0][oc]) | ((unsigned int)f2b(lt[i4 + 1][oc]) << 16);
            o.y = (unsigned int)f2b(lt[i4 + 2][oc]) | ((unsigned int)f2b(lt[i4 + 3][oc]) << 16);
            *(uint2*)(dst + (size_t)oc * CDIM + h * 64 + i4) = o;
        }
    }
}

// ---------------- transpose: feature fp32 [B][C][S] -> seq fp32 [B][S][C] ----
__global__ __launch_bounds__(256) void k_transpose(const float* __restrict__ feat,
                                                   float* __restrict__ seq) {
    __shared__ float lt[128][69];
    int b = blockIdx.x, s0 = blockIdx.y * 64, t = threadIdx.x;
    for (int p = 0; p < 8; ++p) {
        int idx = p * 256 + t;
        int c = idx >> 4, k4 = (idx & 15) * 4;
        float4 u = *(const float4*)(feat + (size_t)b * CDIM * SEQ + (size_t)c * SEQ + s0 + k4);
        lt[c][k4 + 0] = u.x; lt[c][k4 + 1] = u.y;
        lt[c][k4 + 2] = u.z; lt[c][k4 + 3] = u.w;
    }
    __syncthreads();
    for (int p = 0; p < 8; ++p) {
        int w = p * 256 + t;
        int s = w >> 5, c4 = (w & 31) * 4;
        float4 o;
        o.x = lt[c4 + 0][s]; o.y = lt[c4 + 1][s];
        o.z = lt[c4 + 2][s]; o.w = lt[c4 + 3][s];
        *(float4*)(seq + ((size_t)b * SEQ + s0 + s) * CDIM + c4) = o;
    }
}

// ---------------- QKV projection via MFMA -----------------------------------
// seq fp32 -> q,k bf16 [B][S][C]; vT bf16 [B][C][S].  Weights pre-transposed bf16.
__global__ __launch_bounds__(256) void k_qkv(const float* __restrict__ seq,
        const u16* __restrict__ wT,   // this layer: [3][128][128] (q,k,v), [oc][i]
        const float* __restrict__ qb, const float* __restrict__ kb, const float* __restrict__ vb,
        u16* __restrict__ qB, u16* __restrict__ kB, u16* __restrict__ vT) {
    __shared__ __align__(16) u16 lsb[64][136];
    __shared__ __align__(16) u16 lw[128][136];
    u16 (*lvs)[80] = (u16 (*)[80])lw;            // overlay: used only after last lw read
    int b = blockIdx.x, s0 = blockIdx.y * 64, t = threadIdx.x;
    int w = t >> 6, lane = t & 63, col = lane & 15, quad = lane >> 4;

    uint4 wra[8], wrb[8];
    loadw(wT, t, wra);                            // prefetch q-weights
    // stage seq tile -> bf16
    for (int p = 0; p < 8; ++p) {
        int idx = p * 256 + t;
        int r = idx >> 5, c4 = (idx & 31) * 4;
        float4 u = *(const float4*)(seq + ((size_t)b * SEQ + s0 + r) * CDIM + c4);
        uint2 o;
        o.x = (unsigned int)f2b(u.x) | ((unsigned int)f2b(u.y) << 16);
        o.y = (unsigned int)f2b(u.z) | ((unsigned int)f2b(u.w) << 16);
        *(uint2*)(&lsb[r][c4]) = o;
    }
    __syncthreads();
    bf16x8 af[4];
    #pragma unroll
    for (int seg = 0; seg < 4; ++seg)
        af[seg] = *(const bf16x8*)(&lsb[w * 16 + col][seg * 32 + quad * 8]);

    #pragma unroll
    for (int mat = 0; mat < 3; ++mat) {
        if (mat > 0) __syncthreads();             // prior lw reads done
        storew(lw, t, (mat & 1) ? wrb : wra);
        if (mat == 0) loadw(wT + 16384, t, wrb);  // prefetch k
        if (mat == 1) loadw(wT + 32768, t, wra);  // prefetch v
        __syncthreads();
        const float* bias = (mat == 0) ? qb : (mat == 1) ? kb : vb;
        f32x4 acc[8];
        #pragma unroll
        for (int nt = 0; nt < 8; ++nt) {
            float bv = bias[nt * 16 + col];
            acc[nt] = (f32x4){bv, bv, bv, bv};
        }
        #pragma unroll
        for (int nt = 0; nt < 8; ++nt) {
            #pragma unroll
            for (int seg = 0; seg < 4; ++seg) {
                bf16x8 bf = *(const bf16x8*)(&lw[nt * 16 + col][seg * 32 + quad * 8]);
                acc[nt] = __builtin_amdgcn_mfma_f32_16x16x32_bf16(af[seg], bf, acc[nt], 0, 0, 0);
            }
        }
        if (mat < 2) {
            u16* outp = (mat == 0) ? qB : kB;
            #pragma unroll
            for (int nt = 0; nt < 8; ++nt)
                #pragma unroll
                for (int r = 0; r < 4; ++r)
                    outp[((size_t)b * SEQ + s0 + w * 16 + quad * 4 + r) * CDIM + nt * 16 + col] =
                        f2b(acc[nt][r]);
        } else {
            __syncthreads();                       // all lw reads done before overlay write
            #pragma unroll
            for (int nt = 0; nt < 8; ++nt)
                #pragma unroll
                for (int r = 0; r < 4; ++r)
                    lvs[nt * 16 + col][w * 16 + quad * 4 + r] = f2b(acc[nt][r]);
            __syncthreads();
            for (int p = 0; p < 4; ++p) {
                int idx = p * 256 + t;
                int oc = idx >> 3, s8 = (idx & 7) * 8;
                uint4 vv = *(const uint4*)(&lvs[oc][s8]);
                *(uint4*)(vT + ((size_t)b * CDIM + oc) * SEQ + s0 + s8) = vv;
            }
        }
    }
}

// ---------------- flash attention (MFMA bf16), seq += softmax(QK^T*scale)V ---
// 256 threads / 4 waves, TQ=64, register-prefetched K/V tiles.
__global__ __launch_bounds__(256) void k_flash(const u16* __restrict__ qB,
        const u16* __restrict__ kB, const u16* __restrict__ vT,
        float* __restrict__ seq) {
    __shared__ __align__(16) u16 lq[64][136];
    __shared__ __align__(16) u16 lk[64][136];
    __shared__ __align__(16) u16 lvT[128][72];
    __shared__ __align__(16) u16 lsP[64][72];
    int b = blockIdx.x, q0 = blockIdx.y * 64, t = threadIdx.x;
    int w = t >> 6, lane = t & 63, col = lane & 15, quad = lane >> 4;
    const float scale = 0.08838834764831845f;
    size_t bS = (size_t)b * SEQ;
    size_t bCS = (size_t)b * CDIM * SEQ;

    uint4 kr[2][4], vr[2][4];
    #pragma unroll
    for (int j = 0; j < 4; ++j) {                 // prefetch tile 0
        int idx = j * 256 + t;
        int r = idx >> 4, c8 = (idx & 15) * 8;
        kr[0][j] = *(const uint4*)(kB + (bS + r) * CDIM + c8);
        int cc = idx >> 3, k8 = (idx & 7) * 8;
        vr[0][j] = *(const uint4*)(vT + bCS + (size_t)cc * SEQ + k8);
    }
    #pragma unroll
    for (int j = 0; j < 4; ++j) {                 // stage Q tile
        int idx = j * 256 + t;
        int r = idx >> 4, c8 = (idx & 15) * 8;
        *(uint4*)(&lq[r][c8]) = *(const uint4*)(qB + (bS + q0 + r) * CDIM + c8);
    }
    f32x4 occ[8];
    f32x4 zero = {0.f, 0.f, 0.f, 0.f};
    #pragma unroll
    for (int ot = 0; ot < 8; ++ot) occ[ot] = zero;
    float rs_r[4] = {0.f, 0.f, 0.f, 0.f};

    for (int it = 0; it < SEQ / TK / 2; ++it) {
        #pragma unroll
        for (int half = 0; half < 2; ++half) {
            int kc = it * 2 + half;
            __syncthreads();                      // prior compute done with lk/lvT
            #pragma unroll
            for (int j = 0; j < 4; ++j) {         // regs -> LDS
                int idx = j * 256 + t;
                int r = idx >> 4, c8 = (idx & 15) * 8;
                *(uint4*)(&lk[r][c8]) = kr[half][j];
                int cc = idx >> 3, k8 = (idx & 7) * 8;
                *(uint4*)(&lvT[cc][k8]) = vr[half][j];
            }
            if (kc + 1 < SEQ / TK) {              // prefetch next tile during compute
                #pragma unroll
                for (int j = 0; j < 4; ++j) {
                    int idx = j * 256 + t;
                    int r = idx >> 4, c8 = (idx & 15) * 8;
                    kr[half ^ 1][j] = *(const uint4*)(kB + (bS + (kc + 1) * TK + r) * CDIM + c8);
                    int cc = idx >> 3, k8 = (idx & 7) * 8;
                    vr[half ^ 1][j] =
                        *(const uint4*)(vT + bCS + (size_t)cc * SEQ + (kc + 1) * TK + k8);
                }
            }
            __syncthreads();
            // scores: 16 q-rows (this wave) x 64 keys
            f32x4 sacc[4];
            #pragma unroll
            for (int nt = 0; nt < 4; ++nt) sacc[nt] = zero;
            #pragma unroll
            for (int seg = 0; seg < 4; ++seg) {
                bf16x8 a = *(const bf16x8*)(&lq[w * 16 + col][seg * 32 + quad * 8]);
                #pragma unroll
                for (int nt = 0; nt < 4; ++nt) {
                    bf16x8 bb = *(const bf16x8*)(&lk[nt * 16 + col][seg * 32 + quad * 8]);
                    sacc[nt] = __builtin_amdgcn_mfma_f32_16x16x32_bf16(a, bb, sacc[nt], 0, 0, 0);
                }
            }
            #pragma unroll
            for (int nt = 0; nt < 4; ++nt) {
                #pragma unroll
                for (int r = 0; r < 4; ++r) {
                    float pv = __expf(sacc[nt][r] * scale);
                    rs_r[r] += pv;
                    lsP[w * 16 + quad * 4 + r][nt * 16 + col] = f2b(pv);
                }
            }
            #pragma unroll
            for (int seg = 0; seg < 2; ++seg) {
                bf16x8 a = *(const bf16x8*)(&lsP[w * 16 + col][seg * 32 + quad * 8]);
                #pragma unroll
                for (int ot = 0; ot < 8; ++ot) {
                    bf16x8 bb = *(const bf16x8*)(&lvT[ot * 16 + col][seg * 32 + quad * 8]);
                    occ[ot] = __builtin_amdgcn_mfma_f32_16x16x32_bf16(a, bb, occ[ot], 0, 0, 0);
                }
            }
        }
    }
    #pragma unroll
    for (int r = 0; r < 4; ++r) {
        #pragma unroll
        for (int msk = 1; msk < 16; msk <<= 1) rs_r[r] += __shfl_xor(rs_r[r], msk);
    }
    #pragma unroll
    for (int r = 0; r < 4; ++r) {
        float inv = 1.f / rs_r[r];
        int qi = q0 + w * 16 + quad * 4 + r;
        #pragma unroll
        for (int ot = 0; ot < 8; ++ot) {
            int cc = ot * 16 + col;
            size_t adr = ((size_t)b * SEQ + qi) * CDIM + cc;
            seq[adr] += occ[ot][r] * inv;
        }
    }
}

// ---------------- dense MoE + gated combine via MFMA ------------------------
__global__ __launch_bounds__(256) void k_moe(const float* __restrict__ seq,
        const u16* __restrict__ wTm,   // [e][0=w1,1=w2][oc][i] bf16
        const float* __restrict__ eb1, const float* __restrict__ eb2,
        const float* __restrict__ gw, const float* __restrict__ gb,
        float* __restrict__ comb) {
    __shared__ __align__(16) u16 lsb[64][136];   // seq bf16; re-used as h1 after af hoist
    __shared__ __align__(16) u16 lw[128][136];
    __shared__ float lgate[64][4];
    int b = blockIdx.x, s0 = blockIdx.y * 64, t = threadIdx.x;
    int w = t >> 6, lane = t & 63, col = lane & 15, quad = lane >> 4;

    uint4 wra[8], wrb[8];
    loadw(wTm, t, wra);                           // prefetch e0.w1
    for (int p = 0; p < 8; ++p) {
        int idx = p * 256 + t;
        int r = idx >> 5, c4 = (idx & 31) * 4;
        float4 u = *(const float4*)(seq + ((size_t)b * SEQ + s0 + r) * CDIM + c4);
        uint2 o;
        o.x = (unsigned int)f2b(u.x) | ((unsigned int)f2b(u.y) << 16);
        o.y = (unsigned int)f2b(u.z) | ((unsigned int)f2b(u.w) << 16);
        *(uint2*)(&lsb[r][c4]) = o;
    }
    __syncthreads();
    if (t < 192) {                                // gate logits
        int e = t >> 6, s = t & 63;
        float acc = gb[e];
        for (int i = 0; i < CDIM; ++i) acc += b2f(lsb[s][i]) * gw[i * 3 + e];
        lgate[s][e] = acc;
    }
    bf16x8 af[4];
    #pragma unroll
    for (int seg = 0; seg < 4; ++seg)
        af[seg] = *(const bf16x8*)(&lsb[w * 16 + col][seg * 32 + quad * 8]);
    __syncthreads();
    if (t < 64) {                                 // gate softmax
        float a0 = lgate[t][0], a1 = lgate[t][1], a2 = lgate[t][2];
        float mx = fmaxf(a0, fmaxf(a1, a2));
        float e0 = __expf(a0 - mx), e1 = __expf(a1 - mx), e2 = __expf(a2 - mx);
        float inv = 1.f / (e0 + e1 + e2);
        lgate[t][0] = e0 * inv; lgate[t][1] = e1 * inv; lgate[t][2] = e2 * inv;
    }
    f32x4 macc[8];
    f32x4 zero = {0.f, 0.f, 0.f, 0.f};
    #pragma unroll
    for (int nt = 0; nt < 8; ++nt) macc[nt] = zero;

    #pragma unroll
    for (int e = 0; e < NEXP; ++e) {
        // ---- h1 = relu(seq @ w1 + b1) ----
        __syncthreads();                          // prior lw reads done (+gate softmax on e=0)
        storew(lw, t, wra);
        loadw(wTm + (size_t)(2 * e + 1) * 16384, t, wrb);   // prefetch w2
        __syncthreads();
        {
            f32x4 acc[8];
            #pragma unroll
            for (int nt = 0; nt < 8; ++nt) {
                float bv = eb1[e * CDIM + nt * 16 + col];
                acc[nt] = (f32x4){bv, bv, bv, bv};
            }
            #pragma unroll
            for (int nt = 0; nt < 8; ++nt) {
                #pragma unroll
                for (int seg = 0; seg < 4; ++seg) {
                    bf16x8 bf = *(const bf16x8*)(&lw[nt * 16 + col][seg * 32 + quad * 8]);
                    acc[nt] = __builtin_amdgcn_mfma_f32_16x16x32_bf16(af[seg], bf, acc[nt], 0, 0, 0);
                }
            }
            #pragma unroll
            for (int nt = 0; nt < 8; ++nt)
                #pragma unroll
                for (int r = 0; r < 4; ++r)
                    lsb[w * 16 + quad * 4 + r][nt * 16 + col] = f2b(fmaxf(acc[nt][r], 0.f));
        }
        // ---- eo = h1 @ w2 + b2; macc += gate*eo ----
        __syncthreads();                          // all waves done reading lw(w1)
        storew(lw, t, wrb);
        if (e < 2) loadw(wTm + (size_t)(2 * e + 2) * 16384, t, wra);  // prefetch next w1
        __syncthreads();
        {
            bf16x8 a2[4];
            #pragma unroll
            for (int seg = 0; seg < 4; ++seg)
                a2[seg] = *(const bf16x8*)(&lsb[w * 16 + col][seg * 32 + quad * 8]);
            f32x4 acc2[8];
            #pragma unroll
            for (int nt = 0; nt < 8; ++nt) {
                float bv = eb2[e * CDIM + nt * 16 + col];
                acc2[nt] = (f32x4){bv, bv, bv, bv};
            }
            #pragma unroll
            for (int nt = 0; nt < 8; ++nt) {
                #pragma unroll
                for (int seg = 0; seg < 4; ++seg) {
                    bf16x8 bf = *(const bf16x8*)(&lw[nt * 16 + col][seg * 32 + quad * 8]);
                    acc2[nt] = __builtin_amdgcn_mfma_f32_16x16x32_bf16(a2[seg], bf, acc2[nt], 0, 0, 0);
                }
            }
            float gv[4];
            #pragma unroll
            for (int r = 0; r < 4; ++r) gv[r] = lgate[w * 16 + quad * 4 + r][e];
            #pragma unroll
            for (int nt = 0; nt < 8; ++nt)
                #pragma unroll
                for (int r = 0; r < 4; ++r) macc[nt][r] += gv[r] * acc2[nt][r];
        }
    }
    #pragma unroll
    for (int nt = 0; nt < 8; ++nt) {
        #pragma unroll
        for (int r = 0; r < 4; ++r) {
            float mo = macc[nt][r];
            float g = 1.f / (1.f + __expf(-mo));
            size_t adr = ((size_t)b * SEQ + s0 + w * 16 + quad * 4 + r) * CDIM + nt * 16 + col;
            float sv = seq[adr];
            comb[adr] = g * mo + (1.f - g) * sv;
        }
    }
}

// ---------------- hypernet layer 1: hh[b][j] = relu(cond@hw1 + hb1) ---------
__global__ __launch_bounds__(256) void k_h1(const float* __restrict__ cond,
        const float* __restrict__ hw1, const float* __restrict__ hb1,
        float* __restrict__ hh) {
    __shared__ float lcond[8][128];
    int t = threadIdx.x;
    int j = blockIdx.x * 256 + t;
    for (int r = 0; r < 4; ++r) {
        int e = r * 256 + t;
        lcond[e >> 7][e & 127] = cond[e];
    }
    __syncthreads();
    float acc[8];
    float bv = hb1[j];
    #pragma unroll
    for (int bb = 0; bb < 8; ++bb) acc[bb] = bv;
    for (int i = 0; i < CDIM; ++i) {
        float w = hw1[(size_t)i * HHID + j];
        #pragma unroll
        for (int bb = 0; bb < 8; ++bb) acc[bb] += lcond[bb][i] * w;
    }
    #pragma unroll
    for (int bb = 0; bb < 8; ++bb) hh[(size_t)bb * HHID + j] = fmaxf(acc[bb], 0.f);
}

// ---------------- hypernet layer 2 init: wk = hb2 --------------------------
__global__ __launch_bounds__(256) void k_h2init(const float* __restrict__ hb2,
                                                float* __restrict__ wkp) {
    int idx = blockIdx.x * 256 + threadIdx.x;
    wkp[idx] = hb2[idx & (NPAR - 1)];
}

// ---------------- hypernet layer 2: split-K streaming matmul (512 MB read) --
__global__ __launch_bounds__(256) void k_h2(const float* __restrict__ hh,
        const float* __restrict__ hw2, float* __restrict__ wkp) {
    __shared__ float lh[8][256];
    int t = threadIdx.x;
    int n0 = blockIdx.x * 1024 + t * 4;
    int k0 = blockIdx.y * 256;
    for (int p = 0; p < 8; ++p) {
        int idx = p * 256 + t;
        int bb = idx >> 8, k = idx & 255;
        lh[bb][k] = hh[(size_t)bb * HHID + k0 + k];
    }
    __syncthreads();
    f32x4 acc[8];
    f32x4 zero = {0.f, 0.f, 0.f, 0.f};
    #pragma unroll
    for (int bb = 0; bb < 8; ++bb) acc[bb] = zero;
    for (int k = 0; k < 256; ++k) {
        f32x4 w = *(const f32x4*)(hw2 + (size_t)(k0 + k) * NPAR + n0);
        #pragma unroll
        for (int bb = 0; bb < 8; ++bb) acc[bb] += w * lh[bb][k];
    }
    #pragma unroll
    for (int bb = 0; bb < 8; ++bb) {
        #pragma unroll
        for (int j = 0; j < 4; ++j)
            atomicAdd(&wkp[(size_t)bb * NPAR + n0 + j], acc[bb][j]);
    }
}

// ---------------- per-sample 1x1 conv + residual -> out fp32 [B][C][S] ------
__global__ __launch_bounds__(256) void k_conv(const float* __restrict__ comb,
        const float* __restrict__ wkp, float* __restrict__ out) {
    __shared__ float lc[32][132];
    int b = blockIdx.x, s0 = blockIdx.y * 32, t = threadIdx.x;
    for (int p = 0; p < 4; ++p) {
        int idx = p * 256 + t;
        int r = idx >> 5, c4 = (idx & 31) * 4;
        *(float4*)(&lc[r][c4]) = *(const float4*)(comb + ((size_t)b * SEQ + s0 + r) * CDIM + c4);
    }
    __syncthreads();
    int s = t & 31, og = t >> 5;
    #pragma unroll
    for (int j = 0; j < 16; ++j) {
        int oc = og * 16 + j;
        const float* wrow = wkp + (size_t)b * NPAR + oc * CDIM;
        float acc = 0.f;
        for (int i = 0; i < CDIM; i += 4) {
            float4 wv = *(const float4*)(wrow + i);
            float4 cv = *(const float4*)(&lc[s][i]);
            acc += wv.x * cv.x + wv.y * cv.y + wv.z * cv.z + wv.w * cv.w;
        }
        out[(size_t)b * CDIM * SEQ + (size_t)oc * SEQ + s0 + s] = lc[s][oc] + acc;
    }
}

extern "C" void kernel_launch(void* const* d_in, const int* in_sizes, int n_in,
                              void* d_out, int out_size, void* d_ws, size_t ws_size,
                              hipStream_t stream) {
    (void)in_sizes; (void)n_in; (void)out_size; (void)ws_size;
    const float* feat = (const float*)d_in[0];
    const float* cond = (const float*)d_in[1];
    const float* qw = (const float*)d_in[2];
    const float* kw = (const float*)d_in[3];
    const float* vw = (const float*)d_in[4];
    const float* qb = (const float*)d_in[5];
    const float* kb = (const float*)d_in[6];
    const float* vb = (const float*)d_in[7];
    const float* ew1 = (const float*)d_in[8];
    const float* eb1 = (const float*)d_in[9];
    const float* ew2 = (const float*)d_in[10];
    const float* eb2 = (const float*)d_in[11];
    const float* gw = (const float*)d_in[12];
    const float* gb = (const float*)d_in[13];
    const float* hw1 = (const float*)d_in[14];
    const float* hb1 = (const float*)d_in[15];
    const float* hw2 = (const float*)d_in[16];
    const float* hb2 = (const float*)d_in[17];
    float* out = (float*)d_out;

    char* ws = (char*)d_ws;
    float* seq  = (float*)(ws);                     // 9,437,184 B
    float* comb = (float*)(ws + 9437184);           // 9,437,184 B
    u16* qBuf   = (u16*)(ws + 18874368);            // 4,718,592 B
    u16* kBuf   = (u16*)(ws + 23592960);            // 4,718,592 B
    u16* vTbuf  = (u16*)(ws + 28311552);            // 4,718,592 B
    float* hh   = (float*)(ws + 33030144);          //   262,144 B
    float* wkp  = (float*)(ws + 33292288);          //   524,288 B
    u16* wTa    = (u16*)(ws + 33816576);            //   196,608 B (6 attn mats bf16 T)
    u16* wTm    = (u16*)(ws + 34013184);            //   196,608 B (6 moe mats bf16 T)

    k_wprep<<<dim3(12), 256, 0, stream>>>(qw, kw, vw, ew1, ew2, wTa, wTm);
    k_transpose<<<dim3(8, 36), 256, 0, stream>>>(feat, seq);
    for (int l = 0; l < 2; ++l) {
        k_qkv<<<dim3(8, 36), 256, 0, stream>>>(seq, wTa + (size_t)l * 3 * 16384,
                qb + l * CDIM, kb + l * CDIM, vb + l * CDIM, qBuf, kBuf, vTbuf);
        k_flash<<<dim3(8, 36), 256, 0, stream>>>(qBuf, kBuf, vTbuf, seq);
    }
    k_moe<<<dim3(8, 36), 256, 0, stream>>>(seq, wTm, eb1, eb2, gw, gb, comb);
    k_h1<<<dim3(32), 256, 0, stream>>>(cond, hw1, hb1, hh);
    k_h2init<<<dim3(512), 256, 0, stream>>>(hb2, wkp);
    k_h2<<<dim3(16, 32), 256, 0, stream>>>(hh, hw2, wkp);
    k_conv<<<dim3(8, 72), 256, 0, stream>>>(comb, wkp, out);
}